// Round 16
// baseline (1398.154 us; speedup 1.0000x reference)
//
#include <hip/hip_runtime.h>

#define Bk 8
#define Nk 2048
#define Ck 16
#define Dk 64
#define Tk 32
#define GBLK 256
#define NTHR 512
#define SLOT (Bk * 64 * 2048)   // ushorts per vh slot

typedef __attribute__((ext_vector_type(8))) short short8;
typedef __attribute__((ext_vector_type(4))) float floatx4;
typedef __attribute__((ext_vector_type(4))) unsigned uint4v;
typedef unsigned long long u64;
typedef unsigned short u16;

// ---------- LDS layout (dynamic, 512 threads) ----------
// Weights (Wcat, vW1, cw*, cwcat) are read DIRECTLY from global (L2-resident,
// broadcast fragments) — no LDS staging. LDS holds only tiles + small state.
#define OFF_AT   0           // [64][136] bf16  A-tile / chunk buf 0 (+ overlays)
#define OFF_HT   17408       // [64][136] bf16  chunk buf 1 (+ f32 partial-merge overlay)
#define OFF_HROW 34816       // [64][72]  bf16  LSTM h (current step)
#define OFF_CH   44032       // [16][64] f32 chl (current color state, block-local)
#define OFF_GC   48128       // [256] f32 gate const (cm term + biases)
#define OFF_VBS  49152       // [256] f32 v_bih+v_bhh
#define OFF_CBS  50176       // [256] f32 c_bih+c_bhh
#define OFF_VB1  51200       // [112] f32 (pad 128)
#define OFF_VB2  51712       // [64]  f32
#define OFF_CB1  51968       // [112] f32 (pad 128)
#define OFF_CB2  52480       // [64]  f32
#define OFF_W1V  52736       // [16][64] f32 vote W1
#define OFF_B1V  56832       // [16] f32
#define OFF_W2V  56896       // [16] f32
#define OFF_VAC  56960       // [64] f32 vmsg accum (LDS atomics)
#define OFF_VMS  57216       // [64] f32 vmsg_sum (batch)
#define OFF_CMS  57472       // [64] f32 cm_sum
#define OFF_VOT  57728       // [512] f32 vote scratch
#define LDS_TOTAL 59776
// gex overlay ([64][132] f32 = 33792 B) spans AT+HT (34816 B): both dead at that point.

__device__ __forceinline__ float b2f(u16 u) {
  return __uint_as_float(((unsigned)u) << 16);
}
__device__ __forceinline__ u16 f2b(float f) {
  unsigned u = __float_as_uint(f);
  unsigned r = (u + 0x7FFFu + ((u >> 16) & 1u)) >> 16;
  return (u16)r;
}
__device__ __forceinline__ float sigf(float x) { return 1.0f / (1.0f + __expf(-x)); }
__device__ __forceinline__ float tanhf_(float x) { return 2.0f / (1.0f + __expf(-2.0f * x)) - 1.0f; }

// plain vector load via asm (participates in manual vmcnt counting in a1)
__device__ __forceinline__ void ld_b128(uint4v& dst, const void* p) {
  asm volatile("global_load_dwordx4 %0, %1, off" : "=v"(dst) : "v"(p) : "memory");
}
#define WAITVM(n) asm volatile("s_waitcnt vmcnt(" #n ")" ::: "memory")
__device__ __forceinline__ void barrier_lgkm() {
  asm volatile("s_waitcnt lgkmcnt(0)\n\ts_barrier" ::: "memory");
}

// ---------- one-time init kernels ----------
// Parallelized across 64 blocks (grid-stride).
__global__ void k_init_w(const float* vWih, const float* vWhh, const float* cWih, const float* cWhh,
                         const float* vm1, const float* vm2, const float* cm1, const float* cm2,
                         u16* wcat, u16* cwcat, u16* vw1, u16* vw2, u16* cw1, u16* cw2,
                         float* voteAcc, u64* diagBits) {
  const int gtid = blockIdx.x * blockDim.x + threadIdx.x;
  const int gstr = gridDim.x * blockDim.x;
  for (int i = gtid; i < 256 * 128; i += gstr) {
    int g = i >> 7, k = i & 127;
    wcat[i]  = f2b(k < 64 ? vWih[g * 128 + k] : vWhh[g * 64 + (k - 64)]);
    cwcat[i] = f2b(k < 64 ? cWih[g * 64 + k]  : cWhh[g * 64 + (k - 64)]);
  }
  for (int i = gtid; i < 112 * 64; i += gstr) {
    int j = i >> 6, k = i & 63;
    vw1[i] = f2b(j < 100 ? vm1[j * 64 + k] : 0.f);
    cw1[i] = f2b(j < 100 ? cm1[j * 64 + k] : 0.f);
  }
  for (int i = gtid; i < 64 * 128; i += gstr) {
    int d = i >> 7, k = i & 127;
    vw2[i] = f2b(k < 100 ? vm2[d * 100 + k] : 0.f);
    cw2[i] = f2b(k < 100 ? cm2[d * 100 + k] : 0.f);
  }
  if (blockIdx.x == 0) {
    if (threadIdx.x < 8) voteAcc[threadIdx.x] = 0.f;
    if (threadIdx.x < 256) diagBits[threadIdx.x] = 0ull;   // [B][32]
  }
}

// vh slot 0 = v_init broadcast, layout [b][d][n]
__global__ void k_init_vt(const float* vInit, u16* vt0) {
  for (int i = blockIdx.x * blockDim.x + threadIdx.x; i < SLOT; i += gridDim.x * blockDim.x) {
    int d = (i >> 11) & 63;
    vt0[i] = f2b(vInit[d]);
  }
}

// bit-pack A = Mvv(+I); diag flag (Mvv[r][r]) separately. One wave per row.
__global__ void k_bits(const float* Mvv, u64* Abits, u64* diagBits) {
  const int lane = threadIdx.x & 63;
  const int wid = blockIdx.x * 4 + (threadIdx.x >> 6);   // global row in [0, B*N)
  const int b = wid >> 11, n = wid & 2047;
  const float* row = Mvv + (size_t)wid * Nk;
  u64* dst = Abits + (size_t)wid * 32;
  for (int w64 = 0; w64 < 32; ++w64) {
    float v = row[w64 * 64 + lane];
    u64 m = __ballot(v != 0.0f);
    if (lane == 0) {
      if (w64 == (n >> 6)) {
        if ((m >> (n & 63)) & 1ull)
          atomicOr(diagBits + b * 32 + (n >> 6), 1ull << (n & 63));
        m |= 1ull << (n & 63);        // +I self loop
      }
      dst[w64] = m;
    }
  }
}

// ---------- per-step kernel ----------
// All cross-block dataflow (vh, partial, ch/cc) crosses kernel-launch boundaries:
// stream ordering + HSA release/acquire give coherence. No device-side barriers,
// no spins, no system-scope cache ops.
struct SArgs {
  const float *chInit, *vWih;
  const float *vbih, *vbhh, *cbih, *cbhh;
  const float *vmb1, *vmb2, *cmb1, *cmb2;
  const float *voW1, *vob1, *voW2, *vob2;
  const int* ncolors;
  u16* vhbuf;                    // [2][B][64][2048] bf16 ping-pong
  const u64* Abits;              // [B][2048][32]
  const u64* diagBits;           // [B][32]
  float* partial;                // [2][GBLK][64]
  float* vcbuf;                  // [B*2048][64] f32 vertex cell state
  float* chbuf;                  // [2][B][16][64] f32 color h (parity)
  float* ccbuf;                  // [2][B][16][64] f32 color c (parity)
  const u16 *wcat, *cwcat, *vw1, *vw2, *cw1, *cw2;
  float* voteAcc;
  int t;
};

__global__ void __launch_bounds__(NTHR, 1) k_step(SArgs A) {
  extern __shared__ char smem[];
  u16* AtileU = (u16*)(smem + OFF_AT);
  u16* HtileU = (u16*)(smem + OFF_HT);
  u16* HrowU  = (u16*)(smem + OFF_HROW);
  float* chl = (float*)(smem + OFF_CH);
  float* gc  = (float*)(smem + OFF_GC);
  float* vbs = (float*)(smem + OFF_VBS);
  float* cbs = (float*)(smem + OFF_CBS);
  float* vb1 = (float*)(smem + OFF_VB1);
  float* vb2 = (float*)(smem + OFF_VB2);
  float* cb1 = (float*)(smem + OFF_CB1);
  float* cb2 = (float*)(smem + OFF_CB2);
  float* W1v = (float*)(smem + OFF_W1V);
  float* b1v = (float*)(smem + OFF_B1V);
  float* W2v = (float*)(smem + OFF_W2V);
  float* vac = (float*)(smem + OFF_VAC);
  float* vms = (float*)(smem + OFF_VMS);
  float* cms = (float*)(smem + OFF_CMS);
  float* vot = (float*)(smem + OFF_VOT);

  const int t = A.t;
  const int tid = threadIdx.x;
  const int lane = tid & 63;
  const int w = tid >> 6;          // wave id 0..7
  const int rt = w & 3;            // row-tile (16 rows) within block's 64 rows
  const int gh = w >> 2;           // 0 = LOW group (state owner), 1 = HIGH group
  const int q = lane >> 4;         // quad
  const int l15 = lane & 15;
  const int bb = blockIdx.x & 7;             // batch
  const int rb = (blockIdx.x >> 3) * 64;     // row base within batch
  const int ncolv = A.ncolors[bb];
  const floatx4 zf = {0.f, 0.f, 0.f, 0.f};

  // ---- stage small biases/state into LDS (weights stay in global/L2) ----
  if (tid < 112) { vb1[tid] = (tid < 100) ? A.vmb1[tid] : 0.f; cb1[tid] = (tid < 100) ? A.cmb1[tid] : 0.f; }
  if (tid < 64)  { vb2[tid] = A.vmb2[tid]; cb2[tid] = A.cmb2[tid]; vac[tid] = 0.f; }
  if (tid < 256) { vbs[tid] = A.vbih[tid] + A.vbhh[tid]; cbs[tid] = A.cbih[tid] + A.cbhh[tid]; }
  for (int i = tid; i < 1024; i += NTHR) W1v[i] = A.voW1[i];
  if (tid < 16) { b1v[tid] = A.vob1[tid]; W2v[tid] = A.voW2[tid]; }
  const u64 diagbits = A.diagBits[bb * 32 + (rb >> 6)];

  // LOW waves: load h_prev (= vh slot t&1) for own 16 rows; lane = d. 32B contiguous/thread.
  u16 hreg[16];
  if (!gh) {
    const u16* hp = A.vhbuf + (size_t)(t & 1) * SLOT + ((size_t)(bb * 64 + lane)) * 2048 + rb + rt * 16;
#pragma unroll
    for (int r = 0; r < 16; ++r) hreg[r] = hp[r];
  }
  __syncthreads();

  // ================= Phase A: color update (t>=1) + cmsg -> gc =================
  if (t == 0) {
    for (int i = tid; i < 1024; i += NTHR) chl[i] = A.chInit[bb * 1024 + i];
    __syncthreads();
  } else {
    const float* chprev = (t == 1) ? (A.chInit + bb * 1024)
                                   : (A.chbuf + (size_t)((t & 1) ^ 1) * Bk * 1024 + bb * 1024);
    if (tid < 64) {
      float s = 0.f;
      const float* pp = A.partial + (size_t)(((t - 1) & 1) * GBLK) * 64;
      for (int i2 = 0; i2 < 32; ++i2) s += pp[(i2 * 8 + bb) * 64 + tid];
      vms[tid] = s;
    }
    __syncthreads();
    for (int i2 = tid; i2 < 16 * 128; i2 += NTHR) {
      int c = i2 >> 7, kk = i2 & 127;
      float v = (kk < 64) ? ((c < ncolv) ? vms[kk] : 0.f) : chprev[c * 64 + (kk - 64)];
      AtileU[c * 136 + kk] = f2b(v);
    }
    __syncthreads();
    floatx4 cacc[2];
    cacc[0] = zf; cacc[1] = zf;
#pragma unroll
    for (int ks = 0; ks < 4; ++ks) {
      short8 af = *(const short8*)(AtileU + l15 * 136 + ks * 32 + q * 8);
#pragma unroll
      for (int j = 0; j < 2; ++j) {
        short8 bv = *(const short8*)(A.cwcat + (size_t)(((w * 2 + j) * 16 + l15) * 128 + ks * 32 + q * 8));
        cacc[j] = __builtin_amdgcn_mfma_f32_16x16x32_bf16(af, bv, cacc[j], 0, 0, 0);
      }
    }
    __syncthreads();
    float* cgp = (float*)(smem + OFF_AT);   // fp32 overlay for gate exchange
#pragma unroll
    for (int j = 0; j < 2; ++j)
#pragma unroll
      for (int reg = 0; reg < 4; ++reg)
        cgp[(q * 4 + reg) * 260 + (w * 2 + j) * 16 + l15] = cacc[j][reg];
    __syncthreads();
    for (int i2 = tid; i2 < 1024; i2 += NTHR) {
      int c = i2 >> 6, d2 = i2 & 63;
      float iv = cgp[c * 260 + d2] + cbs[d2];
      float fv = cgp[c * 260 + 64 + d2] + cbs[64 + d2];
      float gv = cgp[c * 260 + 128 + d2] + cbs[128 + d2];
      float ov = cgp[c * 260 + 192 + d2] + cbs[192 + d2];
      float ccv = (t == 1) ? 0.f : A.ccbuf[(size_t)((t & 1) ^ 1) * Bk * 1024 + bb * 1024 + i2];
      float cn = sigf(fv) * ccv + sigf(iv) * tanhf_(gv);
      float hn = sigf(ov) * tanhf_(cn);
      chl[i2] = hn;
      if (blockIdx.x < 8) {      // one writer per batch publishes state for next launch
        A.ccbuf[(size_t)(t & 1) * Bk * 1024 + bb * 1024 + i2] = cn;
        A.chbuf[(size_t)(t & 1) * Bk * 1024 + bb * 1024 + i2] = hn;
      }
    }
    __syncthreads();
  }
  // ---- cmsg: c_msg MLP on chl + cm_sum + gate const ----
  for (int i = tid; i < 1024; i += NTHR) { int c = i >> 6, kk = i & 63; AtileU[c * 136 + kk] = f2b(chl[i]); }
  __syncthreads();
  if (w < 7) {          // 7 waves x 16 hidden units = 112
    floatx4 m1a = zf;
#pragma unroll
    for (int ks = 0; ks < 2; ++ks) {
      short8 af = *(const short8*)(AtileU + l15 * 136 + ks * 32 + q * 8);
      short8 b0 = *(const short8*)(A.cw1 + (size_t)((w * 16 + l15) * 64 + ks * 32 + q * 8));
      m1a = __builtin_amdgcn_mfma_f32_16x16x32_bf16(af, b0, m1a, 0, 0, 0);
    }
#pragma unroll
    for (int reg = 0; reg < 4; ++reg) {
      float hv = m1a[reg] + cb1[w * 16 + l15];
      HtileU[(q * 4 + reg) * 136 + w * 16 + l15] = f2b(hv > 0.f ? hv : 0.f);
    }
  }
  if (tid < 128) {
    int r = tid >> 3, c = 112 + (tid & 7) * 2;
    HtileU[r * 136 + c] = 0; HtileU[r * 136 + c + 1] = 0;
  }
  __syncthreads();
  if (w < 4) {
    floatx4 m2 = zf;
#pragma unroll
    for (int ks = 0; ks < 4; ++ks) {
      short8 af = *(const short8*)(HtileU + l15 * 136 + ks * 32 + q * 8);
      short8 bv = *(const short8*)(A.cw2 + (size_t)((w * 16 + l15) * 128 + ks * 32 + q * 8));
      m2 = __builtin_amdgcn_mfma_f32_16x16x32_bf16(af, bv, m2, 0, 0, 0);
    }
    float s2 = 0.f;
#pragma unroll
    for (int reg = 0; reg < 4; ++reg) {
      int c = q * 4 + reg;
      float v = m2[reg] + cb2[w * 16 + l15];
      v = v > 0.f ? v : 0.f;
      if (c < ncolv) s2 += v;
    }
    s2 += __shfl_xor(s2, 16);
    s2 += __shfl_xor(s2, 32);
    if (q == 0) cms[w * 16 + l15] = s2;
  }
  __syncthreads();
  if (tid < 256) {
    float dot = 0.f;
    const float* wr = A.vWih + tid * 128 + 64;    // right half of v_Wih (cm_sum input)
#pragma unroll
    for (int k2 = 0; k2 < 64; ++k2) dot += cms[k2] * wr[k2];
    gc[tid] = dot + vbs[tid];
  }
  __syncthreads();

  // ================= Phase B: a1 = (Mvv+I) @ vh; proven depth-2 pipeline =================
  __builtin_amdgcn_sched_barrier(0);
  const u64* arow = A.Abits + ((size_t)bb * 2048 + rb + rt * 16 + l15) * 32;
  const u16* vtr = A.vhbuf + (size_t)(t & 1) * SLOT + (size_t)bb * 64 * 2048;
  u16* vtw = A.vhbuf + (size_t)((t & 1) ^ 1) * SLOT + (size_t)bb * 64 * 2048;

  floatx4 acc4[4];
#pragma unroll
  for (int nt = 0; nt < 4; ++nt) acc4[nt] = zf;

  uint4v D[2][2];     // data regs: group g -> D[g&1] (2 x 16B per thread)
  uint4v Bts[4];      // bits regs: group g -> Bts[g&3]

  auto issueGroup = [&](int c, uint4v (&Ds)[2], uint4v& Bv) {
    ld_b128(Bv, (const char*)arow + (size_t)c * 16);       // A-bits, L2-cached
    const char* base = (const char*)vtr + (size_t)c * 256;
#pragma unroll
    for (int i = 0; i < 2; ++i) {
      int idx = i * NTHR + tid, d = idx >> 4, j2 = idx & 15;
      ld_b128(Ds[i], base + (size_t)d * 4096 + j2 * 16);   // vh, plain (L2-cached, fresh via launch boundary)
    }
  };
  auto stageGroup = [&](const uint4v (&Ds)[2], u16* buf) {
#pragma unroll
    for (int i = 0; i < 2; ++i) {
      int idx = i * NTHR + tid, d = idx >> 4, j2 = idx & 15;
      *(uint4v*)((char*)buf + (size_t)d * 272 + j2 * 16) = Ds[i];
    }
  };
  auto mfmaChunk = [&](const u16* buf, u64 w0, u64 w1) {
    u64 wsel = gh ? w1 : w0;
#pragma unroll
    for (int ks = 0; ks < 2; ++ks) {
      unsigned byte = (unsigned)(wsel >> (ks * 32 + q * 8)) & 0xFFu;
      short8 af;
#pragma unroll
      for (int j = 0; j < 8; ++j) af[j] = (short)(((byte >> j) & 1u) ? 0x3F80 : 0);
      int kg = gh * 2 + ks;
#pragma unroll
      for (int nt = 0; nt < 4; ++nt) {
        short8 bv = *(const short8*)(buf + (nt * 16 + l15) * 136 + kg * 32 + q * 8);
        acc4[nt] = __builtin_amdgcn_mfma_f32_16x16x32_bf16(af, bv, acc4[nt], 0, 0, 0);
      }
    }
  };

  issueGroup(0, D[0], Bts[0]);
  issueGroup(1, D[1], Bts[1]);
  WAITVM(3);                       // group 0 complete (group 1 in flight)
  stageGroup(D[0], AtileU);
  issueGroup(2, D[0], Bts[2]);
  barrier_lgkm();

#pragma unroll
  for (int c = 0; c < 16; ++c) {
    if (c < 14) { WAITVM(3); } else { WAITVM(0); }       // group c+1 data+bits ready
    if (c < 15) {
      stageGroup(D[(c + 1) & 1], ((c + 1) & 1) ? HtileU : AtileU);
      if (c + 3 < 16) issueGroup(c + 3, D[(c + 1) & 1], Bts[(c + 3) & 3]);
    }
    {
      const uint4v& Bv = Bts[c & 3];
      u64 w0 = ((u64)Bv[1] << 32) | Bv[0];
      u64 w1 = ((u64)Bv[3] << 32) | Bv[2];
      mfmaChunk((c & 1) ? HtileU : AtileU, w0, w1);
    }
    if (c < 15) barrier_lgkm();
  }
  __builtin_amdgcn_sched_barrier(0);
  __syncthreads();  // all chunk compute done; A/H tiles free

  // merge K-partials: HIGH -> HT overlay (fp32, disjoint from AtileU), LOW adds
  {
    float* ptf = (float*)(smem + OFF_HT);
    if (gh) {
#pragma unroll
      for (int nt = 0; nt < 4; ++nt)
#pragma unroll
        for (int reg = 0; reg < 4; ++reg)
          ptf[rt * 1024 + (nt * 4 + reg) * 64 + lane] = acc4[nt][reg];
    }
    __syncthreads();
    if (!gh) {
#pragma unroll
      for (int nt = 0; nt < 4; ++nt)
#pragma unroll
        for (int reg = 0; reg < 4; ++reg)
          acc4[nt][reg] += ptf[rt * 1024 + (nt * 4 + reg) * 64 + lane];
      // h_prev into A-tile cols 64..127 (lane = d, own rows — wave-local)
#pragma unroll
      for (int r = 0; r < 16; ++r) AtileU[(rt * 16 + r) * 136 + 64 + lane] = hreg[r];
      // diag extra add, then write Avh cols 0..63
#pragma unroll
      for (int nt = 0; nt < 4; ++nt) {
#pragma unroll
        for (int reg = 0; reg < 4; ++reg) {
          int m = rt * 16 + q * 4 + reg;
          float fl = (float)((diagbits >> m) & 1ull);
          float hp = b2f(AtileU[m * 136 + 64 + nt * 16 + l15]);
          AtileU[m * 136 + nt * 16 + l15] = f2b(acc4[nt][reg] + fl * hp);
        }
      }
    }
  }
  __syncthreads();   // AtileU [Avh|h] visible to all waves

  // ---- a2: gates = [Avh|vh] @ Wcat^T; B-fragments direct from global (L2-hot)
  floatx4 acc2[8];
#pragma unroll
  for (int j = 0; j < 8; ++j) acc2[j] = zf;
#pragma unroll
  for (int ks = 0; ks < 4; ++ks) {
    short8 af = *(const short8*)(AtileU + (rt * 16 + l15) * 136 + ks * 32 + q * 8);
#pragma unroll
    for (int j = 0; j < 8; ++j) {
      short8 bv = *(const short8*)(A.wcat + (size_t)(((gh * 8 + j) * 16 + l15) * 128 + ks * 32 + q * 8));
      acc2[j] = __builtin_amdgcn_mfma_f32_16x16x32_bf16(af, bv, acc2[j], 0, 0, 0);
    }
  }
  __syncthreads();   // AtileU reads done -> gate-exchange overlay may write
  {
    float* gex = (float*)(smem + OFF_AT);   // [64][132] fp32 overlay (g,o gates; spans AT+HT)
    if (gh) {
#pragma unroll
      for (int j = 0; j < 8; ++j)
#pragma unroll
        for (int reg = 0; reg < 4; ++reg)
          gex[(rt * 16 + q * 4 + reg) * 132 + j * 16 + l15] = acc2[j][reg];
    }
    __syncthreads();
    // ---- LSTM pointwise on LOW waves; vc from global (RMW own rows); h -> HROW
    if (!gh) {
#pragma unroll
      for (int u = 0; u < 4; ++u) {
        const int d2 = u * 16 + l15;
        const float gi = gc[d2], gf2 = gc[64 + d2], gg = gc[128 + d2], go = gc[192 + d2];
#pragma unroll
        for (int reg = 0; reg < 4; ++reg) {
          const int row = rt * 16 + q * 4 + reg;
          size_t vci = ((size_t)(bb * 2048 + rb + row)) * 64 + d2;
          float vcv = (t == 0) ? 0.f : A.vcbuf[vci];
          float iv = acc2[u][reg] + gi;
          float fv = acc2[u + 4][reg] + gf2;
          float gv = gex[row * 132 + u * 16 + l15] + gg;
          float ov = gex[row * 132 + 64 + u * 16 + l15] + go;
          float cn = sigf(fv) * vcv + sigf(iv) * tanhf_(gv);
          A.vcbuf[vci] = cn;
          HrowU[row * 72 + d2] = f2b(sigf(ov) * tanhf_(cn));
        }
      }
    }
  }
  __syncthreads();   // HROW complete; gex dead

  if (t < Tk - 1) {
    // ==== overlap: HIGH publishes vh_new (plain stores) || LOW runs a5/a6 v_msg MLP ====
    if (gh) {
      int lt = tid & 255, d = lt >> 2, rr = (lt & 3) * 16;
      union { u16 s[8]; uint4v v; } p0, p1;
#pragma unroll
      for (int j = 0; j < 8; ++j) {
        p0.s[j] = HrowU[(rr + j) * 72 + d];
        p1.s[j] = HrowU[(rr + 8 + j) * 72 + d];
      }
      u16* dst = vtw + (size_t)d * 2048 + rb + rr;
      *(uint4v*)dst = p0.v;
      *(uint4v*)(dst + 8) = p1.v;
    } else {
      // ---- a5/a6: v_msg MLP + row-reduce (LOW waves); W1 fragments direct from global
      u16* HID = AtileU;           // overlay: hidden acts [64][136] bf16
      floatx4 h1[7];
#pragma unroll
      for (int nt = 0; nt < 7; ++nt) h1[nt] = zf;
#pragma unroll
      for (int ks = 0; ks < 2; ++ks) {
        short8 af = *(const short8*)(HrowU + (rt * 16 + l15) * 72 + ks * 32 + q * 8);
#pragma unroll
        for (int nt = 0; nt < 7; ++nt) {
          short8 bv = *(const short8*)(A.vw1 + (size_t)((nt * 16 + l15) * 64 + ks * 32 + q * 8));
          h1[nt] = __builtin_amdgcn_mfma_f32_16x16x32_bf16(af, bv, h1[nt], 0, 0, 0);
        }
      }
#pragma unroll
      for (int nt = 0; nt < 7; ++nt) {
        float bb1 = vb1[nt * 16 + l15];
#pragma unroll
        for (int reg = 0; reg < 4; ++reg) {
          float hv = h1[nt][reg] + bb1;
          HID[(rt * 16 + q * 4 + reg) * 136 + nt * 16 + l15] = f2b(hv > 0.f ? hv : 0.f);
        }
      }
#pragma unroll
      for (int r = 0; r < 4; ++r) HID[(rt * 16 + q * 4 + r) * 136 + 112 + l15] = 0;

      floatx4 vm[4];
#pragma unroll
      for (int nt = 0; nt < 4; ++nt) vm[nt] = zf;
#pragma unroll
      for (int ks = 0; ks < 4; ++ks) {
        short8 af = *(const short8*)(HID + (rt * 16 + l15) * 136 + ks * 32 + q * 8);
#pragma unroll
        for (int nt = 0; nt < 4; ++nt) {
          short8 bv = *(const short8*)(A.vw2 + (size_t)((nt * 16 + l15) * 128 + ks * 32 + q * 8));
          vm[nt] = __builtin_amdgcn_mfma_f32_16x16x32_bf16(af, bv, vm[nt], 0, 0, 0);
        }
      }
#pragma unroll
      for (int u = 0; u < 4; ++u) {
        float bb2 = vb2[u * 16 + l15];
        float s = 0.f;
#pragma unroll
        for (int reg = 0; reg < 4; ++reg) { float v = vm[u][reg] + bb2; s += (v > 0.f ? v : 0.f); }
        s += __shfl_xor(s, 16);
        s += __shfl_xor(s, 32);
        if (q == 0) atomicAdd(&vac[u * 16 + l15], s);
      }
    }
    __syncthreads();   // vac complete
    if (tid < 64)
      A.partial[(size_t)((t & 1) * GBLK + blockIdx.x) * 64 + tid] = vac[tid];
  } else {
    // ---- final step: vote from HROW; accumulate via device atomics ----
    {
      int r = tid >> 3, p = tid & 7;
      float hj[2] = {0.f, 0.f};
      for (int d2 = 0; d2 < 64; ++d2) {
        float hv = b2f(HrowU[r * 72 + d2]);
        hj[0] += hv * W1v[(p * 2) * 64 + d2];
        hj[1] += hv * W1v[(p * 2 + 1) * 64 + d2];
      }
      float pv = sigf(hj[0] + b1v[p * 2]) * W2v[p * 2] + sigf(hj[1] + b1v[p * 2 + 1]) * W2v[p * 2 + 1];
      vot[tid] = pv;
    }
    __syncthreads();
    if (tid < 64) {
      float vr = A.vob2[0];
#pragma unroll
      for (int k = 0; k < 8; ++k) vr += vot[tid * 8 + k];
      vr += __shfl_xor(vr, 1);
      vr += __shfl_xor(vr, 2);
      vr += __shfl_xor(vr, 4);
      vr += __shfl_xor(vr, 8);
      vr += __shfl_xor(vr, 16);
      vr += __shfl_xor(vr, 32);
      if (tid == 0) atomicAdd(&A.voteAcc[bb], vr);
    }
  }
}

// final: sigmoid(mean) — after all k_step launches (stream-ordered)
__global__ void k_final(const float* voteAcc, float* out) {
  int i = threadIdx.x;
  if (i < 8) out[i] = 1.f / (1.f + __expf(-(voteAcc[i] * (1.f / 2048.f))));
}

// ---------- host ----------
extern "C" void kernel_launch(void* const* d_in, const int* in_sizes, int n_in,
                              void* d_out, int out_size, void* d_ws, size_t ws_size,
                              hipStream_t stream) {
  (void)in_sizes; (void)n_in; (void)out_size; (void)ws_size;
  const float* Mvv    = (const float*)d_in[0];
  const float* chInit = (const float*)d_in[1];
  const float* vInit  = (const float*)d_in[2];
  const float* vWih   = (const float*)d_in[3];
  const float* vWhh   = (const float*)d_in[4];
  const float* vbih   = (const float*)d_in[5];
  const float* vbhh   = (const float*)d_in[6];
  const float* cWih   = (const float*)d_in[7];
  const float* cWhh   = (const float*)d_in[8];
  const float* cbih   = (const float*)d_in[9];
  const float* cbhh   = (const float*)d_in[10];
  const float* cm1    = (const float*)d_in[11];
  const float* cmb1   = (const float*)d_in[12];
  const float* cm2    = (const float*)d_in[13];
  const float* cmb2   = (const float*)d_in[14];
  const float* vm1    = (const float*)d_in[15];
  const float* vmb1   = (const float*)d_in[16];
  const float* vm2    = (const float*)d_in[17];
  const float* vmb2   = (const float*)d_in[18];
  const float* voW1   = (const float*)d_in[19];
  const float* vob1   = (const float*)d_in[20];
  const float* voW2   = (const float*)d_in[21];
  const float* vob2   = (const float*)d_in[22];
  const int*   ncol   = (const int*)d_in[23];

  char* wsb = (char*)d_ws;
  size_t off = 0;
  auto wsAlloc = [&](size_t bytes) -> char* {
    char* p = wsb + off;
    off = (off + bytes + 255) & ~(size_t)255;
    return p;
  };
  float* voteAcc  = (float*)wsAlloc(256);
  u16* vhb        = (u16*)wsAlloc((size_t)2 * SLOT * 2);               // 4 MB
  u64* Abits      = (u64*)wsAlloc((size_t)Bk * Nk * 32 * 8);           // 4 MB
  u64* diagBits   = (u64*)wsAlloc((size_t)Bk * 32 * 8);                // 2 KB
  float* partial  = (float*)wsAlloc((size_t)2 * GBLK * 64 * 4);        // 128 KB
  float* vcbuf    = (float*)wsAlloc((size_t)Bk * Nk * 64 * 4);         // 4 MB
  float* chbuf    = (float*)wsAlloc((size_t)2 * Bk * 1024 * 4);        // 64 KB
  float* ccbuf    = (float*)wsAlloc((size_t)2 * Bk * 1024 * 4);        // 64 KB
  u16* wcat       = (u16*)wsAlloc(256 * 128 * 2);
  u16* cwcat      = (u16*)wsAlloc(256 * 128 * 2);
  u16* vw1        = (u16*)wsAlloc(112 * 64 * 2);
  u16* vw2        = (u16*)wsAlloc(64 * 128 * 2);
  u16* cw1        = (u16*)wsAlloc(112 * 64 * 2);
  u16* cw2        = (u16*)wsAlloc(64 * 128 * 2);

  k_init_w<<<64, 256, 0, stream>>>(vWih, vWhh, cWih, cWhh, vm1, vm2, cm1, cm2,
                                   wcat, cwcat, vw1, vw2, cw1, cw2, voteAcc, diagBits);
  k_init_vt<<<256, 256, 0, stream>>>(vInit, vhb);
  k_bits<<<Bk * Nk / 4, 256, 0, stream>>>(Mvv, Abits, diagBits);

  (void)hipFuncSetAttribute((const void*)k_step,
                            hipFuncAttributeMaxDynamicSharedMemorySize, LDS_TOTAL);
  SArgs sa;
  sa.chInit = chInit; sa.vWih = vWih;
  sa.vbih = vbih; sa.vbhh = vbhh; sa.cbih = cbih; sa.cbhh = cbhh;
  sa.vmb1 = vmb1; sa.vmb2 = vmb2; sa.cmb1 = cmb1; sa.cmb2 = cmb2;
  sa.voW1 = voW1; sa.vob1 = vob1; sa.voW2 = voW2; sa.vob2 = vob2;
  sa.ncolors = ncol;
  sa.vhbuf = vhb; sa.Abits = Abits; sa.diagBits = diagBits;
  sa.partial = partial; sa.vcbuf = vcbuf; sa.chbuf = chbuf; sa.ccbuf = ccbuf;
  sa.wcat = wcat; sa.cwcat = cwcat; sa.vw1 = vw1; sa.vw2 = vw2; sa.cw1 = cw1; sa.cw2 = cw2;
  sa.voteAcc = voteAcc;

  for (int t = 0; t < Tk; ++t) {
    sa.t = t;
    k_step<<<GBLK, NTHR, LDS_TOTAL, stream>>>(sa);
  }
  k_final<<<1, 64, 0, stream>>>(voteAcc, (float*)d_out);
}

// Round 17
// 1264.351 us; speedup vs baseline: 1.1058x; 1.1058x over previous
//
#include <hip/hip_runtime.h>

#define Bk 8
#define Nk 2048
#define Ck 16
#define Dk 64
#define Tk 32
#define GBLK 256
#define NTHR 512
#define SLOT (Bk * 64 * 2048)   // ushorts per vh slot

typedef __attribute__((ext_vector_type(8))) short short8;
typedef __attribute__((ext_vector_type(4))) float floatx4;
typedef __attribute__((ext_vector_type(4))) unsigned uint4v;
typedef unsigned long long u64;
typedef unsigned short u16;

// ---------- LDS layout (dynamic, 512 threads) ----------
#define OFF_WCAT 0           // [256][136] bf16  vertex gate weights (Wih_left|Whh)
#define OFF_VW1  69632       // [112][72]  bf16  vmsg W1 (padded 100->112)
#define OFF_AT   85760       // [64][136]  bf16  A-tile / chunk buf 0 (+ overlays)
#define OFF_HT   103168      // [64][136]  bf16  chunk buf 1 (+ f32 partial-merge overlay)
#define OFF_HROW 120576      // [64][72]   bf16  LSTM h (current step)
#define OFF_CH   129792      // [16][64] f32 chl (current color state, block-local)
#define OFF_GC   137984      // [256] f32 gate const (cm term + biases)
#define OFF_VBS  139008      // [256] f32 v_bih+v_bhh
#define OFF_CBS  140032      // [256] f32 c_bih+c_bhh
#define OFF_VB1  141056      // [112] f32
#define OFF_VB2  141568      // [64]  f32
#define OFF_CB1  141824      // [112] f32
#define OFF_CB2  142336      // [64]  f32
#define OFF_W1V  142592      // [16][64] f32 vote W1
#define OFF_B1V  146688      // [16] f32
#define OFF_W2V  146752      // [16] f32
#define OFF_VAC  146816      // [64] f32 vmsg accum (LDS atomics)
#define OFF_VMS  147072      // [64] f32 vmsg_sum (batch)
#define OFF_CMS  147328      // [64] f32 cm_sum
#define OFF_VOT  147584      // [512] f32 vote scratch
#define LDS_TOTAL 149632

__device__ __forceinline__ float b2f(u16 u) {
  return __uint_as_float(((unsigned)u) << 16);
}
__device__ __forceinline__ u16 f2b(float f) {
  unsigned u = __float_as_uint(f);
  unsigned r = (u + 0x7FFFu + ((u >> 16) & 1u)) >> 16;
  return (u16)r;
}
__device__ __forceinline__ float sigf(float x) { return 1.0f / (1.0f + __expf(-x)); }
__device__ __forceinline__ float tanhf_(float x) { return 2.0f / (1.0f + __expf(-2.0f * x)) - 1.0f; }

// plain vector load via asm (participates in manual vmcnt counting in a1)
__device__ __forceinline__ void ld_b128(uint4v& dst, const void* p) {
  asm volatile("global_load_dwordx4 %0, %1, off" : "=v"(dst) : "v"(p) : "memory");
}
#define WAITVM(n) asm volatile("s_waitcnt vmcnt(" #n ")" ::: "memory")
__device__ __forceinline__ void barrier_lgkm() {
  asm volatile("s_waitcnt lgkmcnt(0)\n\ts_barrier" ::: "memory");
}

// ---------- one-time init kernels ----------
// Parallelized across 64 blocks (grid-stride).
__global__ void k_init_w(const float* vWih, const float* vWhh, const float* cWih, const float* cWhh,
                         const float* vm1, const float* vm2, const float* cm1, const float* cm2,
                         u16* wcat, u16* cwcat, u16* vw1, u16* vw2, u16* cw1, u16* cw2,
                         float* voteAcc, u64* diagBits) {
  const int gtid = blockIdx.x * blockDim.x + threadIdx.x;
  const int gstr = gridDim.x * blockDim.x;
  for (int i = gtid; i < 256 * 128; i += gstr) {
    int g = i >> 7, k = i & 127;
    wcat[i]  = f2b(k < 64 ? vWih[g * 128 + k] : vWhh[g * 64 + (k - 64)]);
    cwcat[i] = f2b(k < 64 ? cWih[g * 64 + k]  : cWhh[g * 64 + (k - 64)]);
  }
  for (int i = gtid; i < 112 * 64; i += gstr) {
    int j = i >> 6, k = i & 63;
    vw1[i] = f2b(j < 100 ? vm1[j * 64 + k] : 0.f);
    cw1[i] = f2b(j < 100 ? cm1[j * 64 + k] : 0.f);
  }
  for (int i = gtid; i < 64 * 128; i += gstr) {
    int d = i >> 7, k = i & 127;
    vw2[i] = f2b(k < 100 ? vm2[d * 100 + k] : 0.f);
    cw2[i] = f2b(k < 100 ? cm2[d * 100 + k] : 0.f);
  }
  if (blockIdx.x == 0) {
    if (threadIdx.x < 8) voteAcc[threadIdx.x] = 0.f;
    if (threadIdx.x < 256) diagBits[threadIdx.x] = 0ull;   // [B][32]
  }
}

// vh slot 0 = v_init broadcast, layout [b][d][n]
__global__ void k_init_vt(const float* vInit, u16* vt0) {
  for (int i = blockIdx.x * blockDim.x + threadIdx.x; i < SLOT; i += gridDim.x * blockDim.x) {
    int d = (i >> 11) & 63;
    vt0[i] = f2b(vInit[d]);
  }
}

// bit-pack A = Mvv(+I); diag flag (Mvv[r][r]) separately. One wave per row.
__global__ void k_bits(const float* Mvv, u64* Abits, u64* diagBits) {
  const int lane = threadIdx.x & 63;
  const int wid = blockIdx.x * 4 + (threadIdx.x >> 6);   // global row in [0, B*N)
  const int b = wid >> 11, n = wid & 2047;
  const float* row = Mvv + (size_t)wid * Nk;
  u64* dst = Abits + (size_t)wid * 32;
  for (int w64 = 0; w64 < 32; ++w64) {
    float v = row[w64 * 64 + lane];
    u64 m = __ballot(v != 0.0f);
    if (lane == 0) {
      if (w64 == (n >> 6)) {
        if ((m >> (n & 63)) & 1ull)
          atomicOr(diagBits + b * 32 + (n >> 6), 1ull << (n & 63));
        m |= 1ull << (n & 63);        // +I self loop
      }
      dst[w64] = m;
    }
  }
}

// ---------- per-step kernel ----------
// All cross-block dataflow (vh, partial, ch/cc) crosses kernel-launch boundaries:
// stream ordering + HSA release/acquire give coherence. No device-side barriers,
// no spins, no system-scope cache ops.
struct SArgs {
  const float *chInit, *vWih;
  const float *vbih, *vbhh, *cbih, *cbhh;
  const float *vmb1, *vmb2, *cmb1, *cmb2;
  const float *voW1, *vob1, *voW2, *vob2;
  const int* ncolors;
  u16* vhbuf;                    // [2][B][64][2048] bf16 ping-pong
  const u64* Abits;              // [B][2048][32]
  const u64* diagBits;           // [B][32]
  float* partial;                // [2][GBLK][64]
  float* vcbuf;                  // [B*2048][64] f32 vertex cell state
  float* chbuf;                  // [2][B][16][64] f32 color h (parity)
  float* ccbuf;                  // [2][B][16][64] f32 color c (parity)
  const u16 *wcat, *cwcat, *vw1, *vw2, *cw1, *cw2;
  float* voteAcc;
  int t;
};

__global__ void __launch_bounds__(NTHR, 1) k_step(SArgs A) {
  extern __shared__ char smem[];
  u16* WcatU  = (u16*)(smem + OFF_WCAT);
  u16* vW1U   = (u16*)(smem + OFF_VW1);
  u16* AtileU = (u16*)(smem + OFF_AT);
  u16* HtileU = (u16*)(smem + OFF_HT);
  u16* HrowU  = (u16*)(smem + OFF_HROW);
  float* chl = (float*)(smem + OFF_CH);
  float* gc  = (float*)(smem + OFF_GC);
  float* vbs = (float*)(smem + OFF_VBS);
  float* cbs = (float*)(smem + OFF_CBS);
  float* vb1 = (float*)(smem + OFF_VB1);
  float* vb2 = (float*)(smem + OFF_VB2);
  float* cb1 = (float*)(smem + OFF_CB1);
  float* cb2 = (float*)(smem + OFF_CB2);
  float* W1v = (float*)(smem + OFF_W1V);
  float* b1v = (float*)(smem + OFF_B1V);
  float* W2v = (float*)(smem + OFF_W2V);
  float* vac = (float*)(smem + OFF_VAC);
  float* vms = (float*)(smem + OFF_VMS);
  float* cms = (float*)(smem + OFF_CMS);
  float* vot = (float*)(smem + OFF_VOT);

  const int t = A.t;
  const int tid = threadIdx.x;
  const int lane = tid & 63;
  const int w = tid >> 6;          // wave id 0..7
  const int rt = w & 3;            // row-tile (16 rows) within block's 64 rows
  const int gh = w >> 2;           // 0 = LOW group (state owner), 1 = HIGH group
  const int q = lane >> 4;         // quad
  const int l15 = lane & 15;
  const int bb = blockIdx.x & 7;             // batch
  const int rb = (blockIdx.x >> 3) * 64;     // row base within batch
  const int ncolv = A.ncolors[bb];
  const floatx4 zf = {0.f, 0.f, 0.f, 0.f};

  // ---- stage weights/biases into LDS (per launch; L2-hot) ----
  for (int i = tid; i < 256 * 128; i += NTHR) { int g = i >> 7, k = i & 127; WcatU[g * 136 + k] = A.wcat[i]; }
  for (int i = tid; i < 112 * 64; i += NTHR)  { int j = i >> 6, k = i & 63;  vW1U[j * 72 + k]  = A.vw1[i]; }
  if (tid < 112) { vb1[tid] = (tid < 100) ? A.vmb1[tid] : 0.f; cb1[tid] = (tid < 100) ? A.cmb1[tid] : 0.f; }
  if (tid < 64)  { vb2[tid] = A.vmb2[tid]; cb2[tid] = A.cmb2[tid]; vac[tid] = 0.f; }
  if (tid < 256) { vbs[tid] = A.vbih[tid] + A.vbhh[tid]; cbs[tid] = A.cbih[tid] + A.cbhh[tid]; }
  for (int i = tid; i < 1024; i += NTHR) W1v[i] = A.voW1[i];
  if (tid < 16) { b1v[tid] = A.vob1[tid]; W2v[tid] = A.voW2[tid]; }
  const u64 diagbits = A.diagBits[bb * 32 + (rb >> 6)];

  // LOW waves: load h_prev (= vh slot t&1) for own 16 rows; lane = d. 32B contiguous/thread.
  u16 hreg[16];
  if (!gh) {
    const u16* hp = A.vhbuf + (size_t)(t & 1) * SLOT + ((size_t)(bb * 64 + lane)) * 2048 + rb + rt * 16;
#pragma unroll
    for (int r = 0; r < 16; ++r) hreg[r] = hp[r];
  }
  __syncthreads();

  // ================= Phase A: color update (t>=1) + cmsg -> gc =================
  if (t == 0) {
    for (int i = tid; i < 1024; i += NTHR) chl[i] = A.chInit[bb * 1024 + i];
    __syncthreads();
  } else {
    const float* chprev = (t == 1) ? (A.chInit + bb * 1024)
                                   : (A.chbuf + (size_t)((t & 1) ^ 1) * Bk * 1024 + bb * 1024);
    if (tid < 64) {
      float s = 0.f;
      const float* pp = A.partial + (size_t)(((t - 1) & 1) * GBLK) * 64;
      for (int i2 = 0; i2 < 32; ++i2) s += pp[(i2 * 8 + bb) * 64 + tid];
      vms[tid] = s;
    }
    __syncthreads();
    for (int i2 = tid; i2 < 16 * 128; i2 += NTHR) {
      int c = i2 >> 7, kk = i2 & 127;
      float v = (kk < 64) ? ((c < ncolv) ? vms[kk] : 0.f) : chprev[c * 64 + (kk - 64)];
      AtileU[c * 136 + kk] = f2b(v);
    }
    __syncthreads();
    floatx4 cacc[2];
    cacc[0] = zf; cacc[1] = zf;
#pragma unroll
    for (int ks = 0; ks < 4; ++ks) {
      short8 af = *(const short8*)(AtileU + l15 * 136 + ks * 32 + q * 8);
#pragma unroll
      for (int j = 0; j < 2; ++j) {
        short8 bv = *(const short8*)(A.cwcat + (size_t)(((w * 2 + j) * 16 + l15) * 128 + ks * 32 + q * 8));
        cacc[j] = __builtin_amdgcn_mfma_f32_16x16x32_bf16(af, bv, cacc[j], 0, 0, 0);
      }
    }
    __syncthreads();
    float* cgp = (float*)(smem + OFF_AT);   // fp32 overlay for gate exchange
#pragma unroll
    for (int j = 0; j < 2; ++j)
#pragma unroll
      for (int reg = 0; reg < 4; ++reg)
        cgp[(q * 4 + reg) * 260 + (w * 2 + j) * 16 + l15] = cacc[j][reg];
    __syncthreads();
    for (int i2 = tid; i2 < 1024; i2 += NTHR) {
      int c = i2 >> 6, d2 = i2 & 63;
      float iv = cgp[c * 260 + d2] + cbs[d2];
      float fv = cgp[c * 260 + 64 + d2] + cbs[64 + d2];
      float gv = cgp[c * 260 + 128 + d2] + cbs[128 + d2];
      float ov = cgp[c * 260 + 192 + d2] + cbs[192 + d2];
      float ccv = (t == 1) ? 0.f : A.ccbuf[(size_t)((t & 1) ^ 1) * Bk * 1024 + bb * 1024 + i2];
      float cn = sigf(fv) * ccv + sigf(iv) * tanhf_(gv);
      float hn = sigf(ov) * tanhf_(cn);
      chl[i2] = hn;
      if (blockIdx.x < 8) {      // one writer per batch publishes state for next launch
        A.ccbuf[(size_t)(t & 1) * Bk * 1024 + bb * 1024 + i2] = cn;
        A.chbuf[(size_t)(t & 1) * Bk * 1024 + bb * 1024 + i2] = hn;
      }
    }
    __syncthreads();
  }
  // ---- cmsg: c_msg MLP on chl + cm_sum + gate const ----
  for (int i = tid; i < 1024; i += NTHR) { int c = i >> 6, kk = i & 63; AtileU[c * 136 + kk] = f2b(chl[i]); }
  __syncthreads();
  if (w < 7) {          // 7 waves x 16 hidden units = 112
    floatx4 m1a = zf;
#pragma unroll
    for (int ks = 0; ks < 2; ++ks) {
      short8 af = *(const short8*)(AtileU + l15 * 136 + ks * 32 + q * 8);
      short8 b0 = *(const short8*)(A.cw1 + (size_t)((w * 16 + l15) * 64 + ks * 32 + q * 8));
      m1a = __builtin_amdgcn_mfma_f32_16x16x32_bf16(af, b0, m1a, 0, 0, 0);
    }
#pragma unroll
    for (int reg = 0; reg < 4; ++reg) {
      float hv = m1a[reg] + cb1[w * 16 + l15];
      HtileU[(q * 4 + reg) * 136 + w * 16 + l15] = f2b(hv > 0.f ? hv : 0.f);
    }
  }
  if (tid < 128) {
    int r = tid >> 3, c = 112 + (tid & 7) * 2;
    HtileU[r * 136 + c] = 0; HtileU[r * 136 + c + 1] = 0;
  }
  __syncthreads();
  if (w < 4) {
    floatx4 m2 = zf;
#pragma unroll
    for (int ks = 0; ks < 4; ++ks) {
      short8 af = *(const short8*)(HtileU + l15 * 136 + ks * 32 + q * 8);
      short8 bv = *(const short8*)(A.cw2 + (size_t)((w * 16 + l15) * 128 + ks * 32 + q * 8));
      m2 = __builtin_amdgcn_mfma_f32_16x16x32_bf16(af, bv, m2, 0, 0, 0);
    }
    float s2 = 0.f;
#pragma unroll
    for (int reg = 0; reg < 4; ++reg) {
      int c = q * 4 + reg;
      float v = m2[reg] + cb2[w * 16 + l15];
      v = v > 0.f ? v : 0.f;
      if (c < ncolv) s2 += v;
    }
    s2 += __shfl_xor(s2, 16);
    s2 += __shfl_xor(s2, 32);
    if (q == 0) cms[w * 16 + l15] = s2;
  }
  __syncthreads();
  if (tid < 256) {
    float dot = 0.f;
    const float* wr = A.vWih + tid * 128 + 64;    // right half of v_Wih (cm_sum input)
#pragma unroll
    for (int k2 = 0; k2 < 64; ++k2) dot += cms[k2] * wr[k2];
    gc[tid] = dot + vbs[tid];
  }
  __syncthreads();

  // ================= Phase B: a1 = (Mvv+I) @ vh; proven depth-2 pipeline =================
  __builtin_amdgcn_sched_barrier(0);
  const u64* arow = A.Abits + ((size_t)bb * 2048 + rb + rt * 16 + l15) * 32;
  const u16* vtr = A.vhbuf + (size_t)(t & 1) * SLOT + (size_t)bb * 64 * 2048;
  u16* vtw = A.vhbuf + (size_t)((t & 1) ^ 1) * SLOT + (size_t)bb * 64 * 2048;

  floatx4 acc4[4];
#pragma unroll
  for (int nt = 0; nt < 4; ++nt) acc4[nt] = zf;

  uint4v D[2][2];     // data regs: group g -> D[g&1] (2 x 16B per thread)
  uint4v Bts[4];      // bits regs: group g -> Bts[g&3]

  auto issueGroup = [&](int c, uint4v (&Ds)[2], uint4v& Bv) {
    ld_b128(Bv, (const char*)arow + (size_t)c * 16);       // A-bits, L2-cached
    const char* base = (const char*)vtr + (size_t)c * 256;
#pragma unroll
    for (int i = 0; i < 2; ++i) {
      int idx = i * NTHR + tid, d = idx >> 4, j2 = idx & 15;
      ld_b128(Ds[i], base + (size_t)d * 4096 + j2 * 16);   // vh, plain (L2-cached, fresh via launch boundary)
    }
  };
  auto stageGroup = [&](const uint4v (&Ds)[2], u16* buf) {
#pragma unroll
    for (int i = 0; i < 2; ++i) {
      int idx = i * NTHR + tid, d = idx >> 4, j2 = idx & 15;
      *(uint4v*)((char*)buf + (size_t)d * 272 + j2 * 16) = Ds[i];
    }
  };
  auto mfmaChunk = [&](const u16* buf, u64 w0, u64 w1) {
    u64 wsel = gh ? w1 : w0;
#pragma unroll
    for (int ks = 0; ks < 2; ++ks) {
      unsigned byte = (unsigned)(wsel >> (ks * 32 + q * 8)) & 0xFFu;
      short8 af;
#pragma unroll
      for (int j = 0; j < 8; ++j) af[j] = (short)(((byte >> j) & 1u) ? 0x3F80 : 0);
      int kg = gh * 2 + ks;
#pragma unroll
      for (int nt = 0; nt < 4; ++nt) {
        short8 bv = *(const short8*)(buf + (nt * 16 + l15) * 136 + kg * 32 + q * 8);
        acc4[nt] = __builtin_amdgcn_mfma_f32_16x16x32_bf16(af, bv, acc4[nt], 0, 0, 0);
      }
    }
  };

  issueGroup(0, D[0], Bts[0]);
  issueGroup(1, D[1], Bts[1]);
  WAITVM(3);                       // group 0 complete (group 1 in flight)
  stageGroup(D[0], AtileU);
  issueGroup(2, D[0], Bts[2]);
  barrier_lgkm();

#pragma unroll
  for (int c = 0; c < 16; ++c) {
    if (c < 14) { WAITVM(3); } else { WAITVM(0); }       // group c+1 data+bits ready
    if (c < 15) {
      stageGroup(D[(c + 1) & 1], ((c + 1) & 1) ? HtileU : AtileU);
      if (c + 3 < 16) issueGroup(c + 3, D[(c + 1) & 1], Bts[(c + 3) & 3]);
    }
    {
      const uint4v& Bv = Bts[c & 3];
      u64 w0 = ((u64)Bv[1] << 32) | Bv[0];
      u64 w1 = ((u64)Bv[3] << 32) | Bv[2];
      mfmaChunk((c & 1) ? HtileU : AtileU, w0, w1);
    }
    if (c < 15) barrier_lgkm();
  }
  __builtin_amdgcn_sched_barrier(0);
  __syncthreads();  // all chunk compute done; A/H tiles free

  // merge K-partials: HIGH -> HT overlay (fp32, disjoint from AtileU), LOW adds
  {
    float* ptf = (float*)(smem + OFF_HT);
    if (gh) {
#pragma unroll
      for (int nt = 0; nt < 4; ++nt)
#pragma unroll
        for (int reg = 0; reg < 4; ++reg)
          ptf[rt * 1024 + (nt * 4 + reg) * 64 + lane] = acc4[nt][reg];
    }
    __syncthreads();
    if (!gh) {
#pragma unroll
      for (int nt = 0; nt < 4; ++nt)
#pragma unroll
        for (int reg = 0; reg < 4; ++reg)
          acc4[nt][reg] += ptf[rt * 1024 + (nt * 4 + reg) * 64 + lane];
      // h_prev into A-tile cols 64..127 (lane = d, own rows — wave-local)
#pragma unroll
      for (int r = 0; r < 16; ++r) AtileU[(rt * 16 + r) * 136 + 64 + lane] = hreg[r];
      // diag extra add, then write Avh cols 0..63
#pragma unroll
      for (int nt = 0; nt < 4; ++nt) {
#pragma unroll
        for (int reg = 0; reg < 4; ++reg) {
          int m = rt * 16 + q * 4 + reg;
          float fl = (float)((diagbits >> m) & 1ull);
          float hp = b2f(AtileU[m * 136 + 64 + nt * 16 + l15]);
          AtileU[m * 136 + nt * 16 + l15] = f2b(acc4[nt][reg] + fl * hp);
        }
      }
    }
  }
  __syncthreads();   // AtileU [Avh|h] visible to all waves

  // ---- a2: gates = [Avh|vh] @ Wcat^T; pair-split over gates (LOW: i,f  HIGH: g,o)
  floatx4 acc2[8];
#pragma unroll
  for (int j = 0; j < 8; ++j) acc2[j] = zf;
#pragma unroll
  for (int ks = 0; ks < 4; ++ks) {
    short8 af = *(const short8*)(AtileU + (rt * 16 + l15) * 136 + ks * 32 + q * 8);
#pragma unroll
    for (int j = 0; j < 8; ++j) {
      short8 bv = *(const short8*)(WcatU + ((gh * 8 + j) * 16 + l15) * 136 + ks * 32 + q * 8);
      acc2[j] = __builtin_amdgcn_mfma_f32_16x16x32_bf16(af, bv, acc2[j], 0, 0, 0);
    }
  }
  __syncthreads();   // AtileU reads done -> gate-exchange overlay may write
  {
    float* gex = (float*)(smem + OFF_AT);   // [64][132] fp32 overlay (g,o gates)
    if (gh) {
#pragma unroll
      for (int j = 0; j < 8; ++j)
#pragma unroll
        for (int reg = 0; reg < 4; ++reg)
          gex[(rt * 16 + q * 4 + reg) * 132 + j * 16 + l15] = acc2[j][reg];
    }
    __syncthreads();
    // ---- LSTM pointwise on LOW waves; vc from global (RMW own rows); h -> HROW
    if (!gh) {
#pragma unroll
      for (int u = 0; u < 4; ++u) {
        const int d2 = u * 16 + l15;
        const float gi = gc[d2], gf2 = gc[64 + d2], gg = gc[128 + d2], go = gc[192 + d2];
#pragma unroll
        for (int reg = 0; reg < 4; ++reg) {
          const int row = rt * 16 + q * 4 + reg;
          size_t vci = ((size_t)(bb * 2048 + rb + row)) * 64 + d2;
          float vcv = (t == 0) ? 0.f : A.vcbuf[vci];
          float iv = acc2[u][reg] + gi;
          float fv = acc2[u + 4][reg] + gf2;
          float gv = gex[row * 132 + u * 16 + l15] + gg;
          float ov = gex[row * 132 + 64 + u * 16 + l15] + go;
          float cn = sigf(fv) * vcv + sigf(iv) * tanhf_(gv);
          A.vcbuf[vci] = cn;
          HrowU[row * 72 + d2] = f2b(sigf(ov) * tanhf_(cn));
        }
      }
    }
  }
  __syncthreads();   // HROW complete; gex dead

  if (t < Tk - 1) {
    // ==== overlap: HIGH publishes vh_new (plain stores) || LOW runs a5/a6 v_msg MLP ====
    if (gh) {
      int lt = tid & 255, d = lt >> 2, rr = (lt & 3) * 16;
      union { u16 s[8]; uint4v v; } p0, p1;
#pragma unroll
      for (int j = 0; j < 8; ++j) {
        p0.s[j] = HrowU[(rr + j) * 72 + d];
        p1.s[j] = HrowU[(rr + 8 + j) * 72 + d];
      }
      u16* dst = vtw + (size_t)d * 2048 + rb + rr;
      *(uint4v*)dst = p0.v;
      *(uint4v*)(dst + 8) = p1.v;
    } else {
      // ---- a5/a6: v_msg MLP + row-reduce (LOW waves)
      u16* HID = AtileU;           // overlay: hidden acts [64][136] bf16
      floatx4 h1[7];
#pragma unroll
      for (int nt = 0; nt < 7; ++nt) h1[nt] = zf;
#pragma unroll
      for (int ks = 0; ks < 2; ++ks) {
        short8 af = *(const short8*)(HrowU + (rt * 16 + l15) * 72 + ks * 32 + q * 8);
#pragma unroll
        for (int nt = 0; nt < 7; ++nt) {
          short8 bv = *(const short8*)(vW1U + (nt * 16 + l15) * 72 + ks * 32 + q * 8);
          h1[nt] = __builtin_amdgcn_mfma_f32_16x16x32_bf16(af, bv, h1[nt], 0, 0, 0);
        }
      }
#pragma unroll
      for (int nt = 0; nt < 7; ++nt) {
        float bb1 = vb1[nt * 16 + l15];
#pragma unroll
        for (int reg = 0; reg < 4; ++reg) {
          float hv = h1[nt][reg] + bb1;
          HID[(rt * 16 + q * 4 + reg) * 136 + nt * 16 + l15] = f2b(hv > 0.f ? hv : 0.f);
        }
      }
#pragma unroll
      for (int r = 0; r < 4; ++r) HID[(rt * 16 + q * 4 + r) * 136 + 112 + l15] = 0;

      floatx4 vm[4];
#pragma unroll
      for (int nt = 0; nt < 4; ++nt) vm[nt] = zf;
#pragma unroll
      for (int ks = 0; ks < 4; ++ks) {
        short8 af = *(const short8*)(HID + (rt * 16 + l15) * 136 + ks * 32 + q * 8);
#pragma unroll
        for (int nt = 0; nt < 4; ++nt) {
          short8 bv = *(const short8*)(A.vw2 + (size_t)((nt * 16 + l15) * 128 + ks * 32 + q * 8));
          vm[nt] = __builtin_amdgcn_mfma_f32_16x16x32_bf16(af, bv, vm[nt], 0, 0, 0);
        }
      }
#pragma unroll
      for (int u = 0; u < 4; ++u) {
        float bb2 = vb2[u * 16 + l15];
        float s = 0.f;
#pragma unroll
        for (int reg = 0; reg < 4; ++reg) { float v = vm[u][reg] + bb2; s += (v > 0.f ? v : 0.f); }
        s += __shfl_xor(s, 16);
        s += __shfl_xor(s, 32);
        if (q == 0) atomicAdd(&vac[u * 16 + l15], s);
      }
    }
    __syncthreads();   // vac complete
    if (tid < 64)
      A.partial[(size_t)((t & 1) * GBLK + blockIdx.x) * 64 + tid] = vac[tid];
  } else {
    // ---- final step: vote from HROW; accumulate via device atomics ----
    {
      int r = tid >> 3, p = tid & 7;
      float hj[2] = {0.f, 0.f};
      for (int d2 = 0; d2 < 64; ++d2) {
        float hv = b2f(HrowU[r * 72 + d2]);
        hj[0] += hv * W1v[(p * 2) * 64 + d2];
        hj[1] += hv * W1v[(p * 2 + 1) * 64 + d2];
      }
      float pv = sigf(hj[0] + b1v[p * 2]) * W2v[p * 2] + sigf(hj[1] + b1v[p * 2 + 1]) * W2v[p * 2 + 1];
      vot[tid] = pv;
    }
    __syncthreads();
    if (tid < 64) {
      float vr = A.vob2[0];
#pragma unroll
      for (int k = 0; k < 8; ++k) vr += vot[tid * 8 + k];
      vr += __shfl_xor(vr, 1);
      vr += __shfl_xor(vr, 2);
      vr += __shfl_xor(vr, 4);
      vr += __shfl_xor(vr, 8);
      vr += __shfl_xor(vr, 16);
      vr += __shfl_xor(vr, 32);
      if (tid == 0) atomicAdd(&A.voteAcc[bb], vr);
    }
  }
}

// final: sigmoid(mean) — after all k_step launches (stream-ordered)
__global__ void k_final(const float* voteAcc, float* out) {
  int i = threadIdx.x;
  if (i < 8) out[i] = 1.f / (1.f + __expf(-(voteAcc[i] * (1.f / 2048.f))));
}

// ---------- host ----------
extern "C" void kernel_launch(void* const* d_in, const int* in_sizes, int n_in,
                              void* d_out, int out_size, void* d_ws, size_t ws_size,
                              hipStream_t stream) {
  (void)in_sizes; (void)n_in; (void)out_size; (void)ws_size;
  const float* Mvv    = (const float*)d_in[0];
  const float* chInit = (const float*)d_in[1];
  const float* vInit  = (const float*)d_in[2];
  const float* vWih   = (const float*)d_in[3];
  const float* vWhh   = (const float*)d_in[4];
  const float* vbih   = (const float*)d_in[5];
  const float* vbhh   = (const float*)d_in[6];
  const float* cWih   = (const float*)d_in[7];
  const float* cWhh   = (const float*)d_in[8];
  const float* cbih   = (const float*)d_in[9];
  const float* cbhh   = (const float*)d_in[10];
  const float* cm1    = (const float*)d_in[11];
  const float* cmb1   = (const float*)d_in[12];
  const float* cm2    = (const float*)d_in[13];
  const float* cmb2   = (const float*)d_in[14];
  const float* vm1    = (const float*)d_in[15];
  const float* vmb1   = (const float*)d_in[16];
  const float* vm2    = (const float*)d_in[17];
  const float* vmb2   = (const float*)d_in[18];
  const float* voW1   = (const float*)d_in[19];
  const float* vob1   = (const float*)d_in[20];
  const float* voW2   = (const float*)d_in[21];
  const float* vob2   = (const float*)d_in[22];
  const int*   ncol   = (const int*)d_in[23];

  char* wsb = (char*)d_ws;
  size_t off = 0;
  auto wsAlloc = [&](size_t bytes) -> char* {
    char* p = wsb + off;
    off = (off + bytes + 255) & ~(size_t)255;
    return p;
  };
  float* voteAcc  = (float*)wsAlloc(256);
  u16* vhb        = (u16*)wsAlloc((size_t)2 * SLOT * 2);               // 4 MB
  u64* Abits      = (u64*)wsAlloc((size_t)Bk * Nk * 32 * 8);           // 4 MB
  u64* diagBits   = (u64*)wsAlloc((size_t)Bk * 32 * 8);                // 2 KB
  float* partial  = (float*)wsAlloc((size_t)2 * GBLK * 64 * 4);        // 128 KB
  float* vcbuf    = (float*)wsAlloc((size_t)Bk * Nk * 64 * 4);         // 4 MB
  float* chbuf    = (float*)wsAlloc((size_t)2 * Bk * 1024 * 4);        // 64 KB
  float* ccbuf    = (float*)wsAlloc((size_t)2 * Bk * 1024 * 4);        // 64 KB
  u16* wcat       = (u16*)wsAlloc(256 * 128 * 2);
  u16* cwcat      = (u16*)wsAlloc(256 * 128 * 2);
  u16* vw1        = (u16*)wsAlloc(112 * 64 * 2);
  u16* vw2        = (u16*)wsAlloc(64 * 128 * 2);
  u16* cw1        = (u16*)wsAlloc(112 * 64 * 2);
  u16* cw2        = (u16*)wsAlloc(64 * 128 * 2);

  k_init_w<<<64, 256, 0, stream>>>(vWih, vWhh, cWih, cWhh, vm1, vm2, cm1, cm2,
                                   wcat, cwcat, vw1, vw2, cw1, cw2, voteAcc, diagBits);
  k_init_vt<<<256, 256, 0, stream>>>(vInit, vhb);
  k_bits<<<Bk * Nk / 4, 256, 0, stream>>>(Mvv, Abits, diagBits);

  (void)hipFuncSetAttribute((const void*)k_step,
                            hipFuncAttributeMaxDynamicSharedMemorySize, LDS_TOTAL);
  SArgs sa;
  sa.chInit = chInit; sa.vWih = vWih;
  sa.vbih = vbih; sa.vbhh = vbhh; sa.cbih = cbih; sa.cbhh = cbhh;
  sa.vmb1 = vmb1; sa.vmb2 = vmb2; sa.cmb1 = cmb1; sa.cmb2 = cmb2;
  sa.voW1 = voW1; sa.vob1 = vob1; sa.voW2 = voW2; sa.vob2 = vob2;
  sa.ncolors = ncol;
  sa.vhbuf = vhb; sa.Abits = Abits; sa.diagBits = diagBits;
  sa.partial = partial; sa.vcbuf = vcbuf; sa.chbuf = chbuf; sa.ccbuf = ccbuf;
  sa.wcat = wcat; sa.cwcat = cwcat; sa.vw1 = vw1; sa.vw2 = vw2; sa.cw1 = cw1; sa.cw2 = cw2;
  sa.voteAcc = voteAcc;

  for (int t = 0; t < Tk; ++t) {
    sa.t = t;
    k_step<<<GBLK, NTHR, LDS_TOTAL, stream>>>(sa);
  }
  k_final<<<1, 64, 0, stream>>>(voteAcc, (float*)d_out);
}